// Round 11
// baseline (1274.032 us; speedup 1.0000x reference)
//
#include <hip/hip_runtime.h>
#include <hip/hip_bf16.h>
#include <stdint.h>

// AWQ GEMM: out[2048,11008](f32) = x[2048,4096](f32,f16-valued) @ dequant4(...) + bias
// Round 11: r8 body (BM=256, 512 thr, f16 fast-dequant, XOR-swizzled LDS) but
// SINGLE-buffered LDS (48 KB) -> 2 blocks/CU (16 waves, 4/SIMD from independent
// blocks; cross-block MFMA||VALU overlap, m114). r10's phase/setprio graft was
// negative (no async-load mechanism to span barriers); r8's dbuf bought nothing
// at 1 block/CU because all waves were barrier-locked in the same phase anyway.
// Schedule/iter: [issue global loads k+1] [compute k] [sync] [dequant+write k+1] [sync].

constexpr int IN_F   = 4096;
constexpr int OUT_F  = 11008;
constexpr int PCOLS  = OUT_F / 8;   // 1376
constexpr int BM = 256, BN = 128, BK = 64;
constexpr int NKT    = IN_F / BK;   // 64
constexpr int NTILES = OUT_F / BN;  // 86
constexpr int ABYTES = BM * BK * 2; // 32768
constexpr int BBYTES = BN * BK * 2; // 16384

typedef _Float16 h2 __attribute__((ext_vector_type(2)));
typedef _Float16 h8 __attribute__((ext_vector_type(8)));
typedef float f32x4  __attribute__((ext_vector_type(4)));

__device__ __forceinline__ h2 pkh2(float a, float b) {
    return __builtin_bit_cast(h2, __builtin_amdgcn_cvt_pkrtz(a, b));
}
__device__ __forceinline__ unsigned int pk2(float a, float b) {
    return __builtin_bit_cast(unsigned int, __builtin_amdgcn_cvt_pkrtz(a, b));
}

__global__ __launch_bounds__(512, 4)
void awq_gemm_kernel(const float* __restrict__ X,
                     const int*   __restrict__ QW,
                     const int*   __restrict__ QZ,
                     const float* __restrict__ S,
                     const float* __restrict__ BIAS,
                     float*       __restrict__ O)
{
    // single buffer: A [256 rows][128B] then B [128 cols][128B]  (48 KB)
    // A: k-octet o of row r at 16B slot o^(r&7)
    // B: k-octet o of col n at 16B slot o^(n&7)^((n>>3)&7)
    __shared__ alignas(16) unsigned char smem[ABYTES + BBYTES];

    const int t    = threadIdx.x;
    const int lane = t & 63;
    const int w    = t >> 6;      // 0..7
    const int wm   = w >> 1;      // 0..3 (row block of 64)
    const int wn   = w & 1;       // 0..1 (col block of 64)
    const int l15 = lane & 15, l45 = lane >> 4, l7 = lane & 7, l3 = (lane >> 3) & 1;

    // XCD mapping: XCD x (= bid&7) owns mtile x; sweeps all 86 ntiles. 688 = 8*86.
    const int bid   = blockIdx.x;
    const int mtile = bid & 7;
    const int ntile = bid >> 3;
    const int m0 = mtile * BM;
    const int n0 = ntile * BN;
    const int P0 = n0 >> 3;

    // ---- A staging: thread covers rows (t>>3)+64i, k-octet t&7 ----
    const int arow = t >> 3;              // 0..63
    const int aoct = t & 7;
    const int aphys = aoct ^ (arow & 7);  // 64i preserves row&7
    const float* Xb = X + (size_t)(m0 + arow) * IN_F + aoct * 8;

    float4 areg[4][2];
    auto load_A = [&](int kt) {
#pragma unroll
        for (int i = 0; i < 4; ++i) {
            const float* p = Xb + (size_t)i * 64 * IN_F + kt * BK;
            areg[i][0] = *(const float4*)(p);
            areg[i][1] = *(const float4*)(p + 4);
        }
    };
    auto write_A = [&]() {
        unsigned char* ab = smem;
#pragma unroll
        for (int i = 0; i < 4; ++i) {
            uint4 v;
            v.x = pk2(areg[i][0].x, areg[i][0].y);
            v.y = pk2(areg[i][0].z, areg[i][0].w);
            v.z = pk2(areg[i][1].x, areg[i][1].y);
            v.w = pk2(areg[i][1].z, areg[i][1].w);
            *(uint4*)(ab + (i * 64 + arow) * 128 + aphys * 16) = v;
        }
    };

    // ---- B staging: thread covers packed col pcol = t&15, k-pair 2kd, 2kd+1 (kd = t>>4) ----
    const int pcol = t & 15;
    const int kd   = t >> 4;         // 0..31
    const int pc7  = pcol & 7;
    const int ob   = kd >> 2;        // k-octet
    const int sub  = (kd & 3) * 4;   // byte offset within 16B slot
    const int* qwb = QW + (size_t)(2 * kd) * PCOLS + P0 + pcol;
    const unsigned int* qzc = (const unsigned int*)QZ + P0 + pcol;
    const float* scol = S + n0 + pcol * 8;

    constexpr int SH[8]  = {0, 16, 4, 20, 8, 24, 12, 28}; // shift of logical nibble j
    constexpr int JLO[4] = {0, 4, 1, 5};                  // low-nibble j of byte b

    h2 spk[8], zpk[8];
    unsigned int zraw_n; float4 sv0, sv1;
    unsigned int raw0, raw1;

    auto load_group = [&](int g) {
        zraw_n = qzc[(size_t)g * PCOLS];
        sv0 = *(const float4*)(scol + (size_t)g * OUT_F);
        sv1 = *(const float4*)(scol + (size_t)g * OUT_F + 4);
    };
    auto compute_group = [&]() {
        const float sf[8] = {sv0.x, sv0.y, sv0.z, sv0.w, sv1.x, sv1.y, sv1.z, sv1.w};
#pragma unroll
        for (int j = 0; j < 8; ++j) {
            float zb = 1024.0f + (float)((zraw_n >> SH[j]) & 15u);  // exact in f16
            spk[j] = pkh2(sf[j], sf[j]);
            zpk[j] = pkh2(zb, zb);
        }
    };
    auto load_raws = [&](int kt) {
        const size_t off = (size_t)kt * BK * PCOLS;
        raw0 = (unsigned int)qwb[off];
        raw1 = (unsigned int)qwb[off + PCOLS];
    };
    auto stage_B = [&]() {
        unsigned char* bb = smem + ABYTES;
#pragma unroll
        for (int b = 0; b < 4; ++b) {
            const int jl = JLO[b], jh = jl + 2;
            // byte b of raw0 -> dst byte0, byte b of raw1 -> dst byte2 (others masked)
            unsigned int d  = __builtin_amdgcn_perm(raw1, raw0,
                                 (unsigned int)(((4 + b) << 16) | b));
            unsigned int lo = (d & 0x000F000Fu) | 0x64006400u;         // (1024+q) pair, j=jl
            unsigned int hi = ((d >> 4) & 0x000F000Fu) | 0x64006400u;  // j=jh
            // exact sub (both exact ints in f16), then single f16 rounding on mul
            h2 wl = (__builtin_bit_cast(h2, lo) - zpk[jl]) * spk[jl];
            h2 wh = (__builtin_bit_cast(h2, hi) - zpk[jh]) * spk[jh];
            const int nl = pcol * 8 + jl, nh = pcol * 8 + jh;
            *(unsigned int*)(bb + nl * 128 + ((ob ^ jl ^ pc7) * 16) + sub) =
                __builtin_bit_cast(unsigned int, wl);
            *(unsigned int*)(bb + nh * 128 + ((ob ^ jh ^ pc7) * 16) + sub) =
                __builtin_bit_cast(unsigned int, wh);
        }
    };

    f32x4 acc[4][4];
#pragma unroll
    for (int mi = 0; mi < 4; ++mi)
#pragma unroll
        for (int ni = 0; ni < 4; ++ni)
            acc[mi][ni] = f32x4{0.f, 0.f, 0.f, 0.f};

    auto compute_tile = [&]() {
        const unsigned char* ab = smem;
        const unsigned char* bb = smem + ABYTES;
#pragma unroll
        for (int ks = 0; ks < 2; ++ks) {
            h8 a[4], bf[4];
#pragma unroll
            for (int mi = 0; mi < 4; ++mi) {
                int off = (wm * 64 + mi * 16 + l15) * 128
                        + (((ks * 4 + l45) ^ l7) * 16);          // row&7 == l7
                a[mi] = *(const h8*)(ab + off);
            }
#pragma unroll
            for (int ni = 0; ni < 4; ++ni) {
                int off = (wn * 64 + ni * 16 + l15) * 128
                        + ((((ks * 4 + l45) ^ l7 ^ l3) ^ (2 * ni)) * 16); // n&7==l7
                bf[ni] = *(const h8*)(bb + off);
            }
#pragma unroll
            for (int mi = 0; mi < 4; ++mi)
#pragma unroll
                for (int ni = 0; ni < 4; ++ni)
                    acc[mi][ni] = __builtin_amdgcn_mfma_f32_16x16x32_f16(
                        a[mi], bf[ni], acc[mi][ni], 0, 0, 0);
        }
    };

    // ---- prologue: stage tile 0 ----
    load_A(0);
    load_raws(0);
    load_group(0);
    compute_group();
    write_A();
    stage_B();
    __syncthreads();

    // ---- main loop: single buffer, 2 barriers/iter ----
    // [issue loads k+1 (VMEM, covered by compute)] [compute k] [sync: reads done]
    // [dequant+write k+1] [sync: writes done]
#pragma unroll 1
    for (int kt = 0; kt < NKT; ++kt) {
        if (kt + 1 < NKT) {
            load_A(kt + 1);                    // issue-early (T14), lands in regs
            load_raws(kt + 1);
            if (((kt + 1) & 1) == 0) load_group((kt + 1) >> 1);
        }
        compute_tile();
        __syncthreads();                       // all reads of buffer complete
        if (kt + 1 < NKT) {
            if (((kt + 1) & 1) == 0) compute_group();
            write_A();
            stage_B();
        }
        __syncthreads();                       // all writes complete
    }

    // ---- epilogue: bias + f32 store (C/D: col=lane&15, row=(lane>>4)*4+reg) ----
    const int orow0 = m0 + wm * 64 + l45 * 4;
    const int ocol0 = n0 + wn * 64 + l15;
    float bv[4];
#pragma unroll
    for (int ni = 0; ni < 4; ++ni)
        bv[ni] = BIAS[ocol0 + ni * 16];
#pragma unroll
    for (int mi = 0; mi < 4; ++mi)
#pragma unroll
        for (int ni = 0; ni < 4; ++ni)
#pragma unroll
            for (int r = 0; r < 4; ++r) {
                int row = orow0 + mi * 16 + r;
                int col = ocol0 + ni * 16;
                O[(size_t)row * OUT_F + col] = acc[mi][ni][r] + bv[ni];
            }
}

extern "C" void kernel_launch(void* const* d_in, const int* in_sizes, int n_in,
                              void* d_out, int out_size, void* d_ws, size_t ws_size,
                              hipStream_t stream) {
    const float* X  = (const float*)d_in[0];
    const int*   QW = (const int*)d_in[1];
    const int*   QZ = (const int*)d_in[2];
    const float* S  = (const float*)d_in[3];
    const float* Bi = (const float*)d_in[4];
    float*       O  = (float*)d_out;

    dim3 grid(8 * NTILES);   // 688
    dim3 block(512);
    awq_gemm_kernel<<<grid, block, 0, stream>>>(X, QW, QZ, S, Bi, O);
}

// Round 12
// 283.709 us; speedup vs baseline: 4.4906x; 4.4906x over previous
//
#include <hip/hip_runtime.h>
#include <hip/hip_bf16.h>
#include <stdint.h>

// AWQ GEMM: out[2048,11008](f32) = x[2048,4096](f32,f16-valued) @ dequant4(...) + bias
// Round 12: r8 body (BM=256, 512 thr, f16 fast-dequant, XOR-swizzled LDS,
// launch_bounds(512,2) -> 120 VGPR, NO spill) with LDS cut 96->64 KB so TWO
// blocks fit per CU (16 waves, 4/SIMD, cross-block MFMA||VALU overlap):
//   A tile single-buffered (32 KB), B tile double-buffered (2x16 KB).
// stage_B(k+1) issues BEFORE the first barrier (writes B-buf[cur^1], disjoint
// from B[cur] reads); only write_A sits between the two barriers.
// r11 lesson: launch_bounds(512,4) makes the compiler pick 64 VGPR -> 26x
// scratch traffic. Keep (512,2).

constexpr int IN_F   = 4096;
constexpr int OUT_F  = 11008;
constexpr int PCOLS  = OUT_F / 8;   // 1376
constexpr int BM = 256, BN = 128, BK = 64;
constexpr int NKT    = IN_F / BK;   // 64
constexpr int NTILES = OUT_F / BN;  // 86
constexpr int ABYTES = BM * BK * 2; // 32768 (single buffer)
constexpr int BBYTES = BN * BK * 2; // 16384 (x2 buffers)

typedef _Float16 h2 __attribute__((ext_vector_type(2)));
typedef _Float16 h8 __attribute__((ext_vector_type(8)));
typedef float f32x4  __attribute__((ext_vector_type(4)));

__device__ __forceinline__ h2 pkh2(float a, float b) {
    return __builtin_bit_cast(h2, __builtin_amdgcn_cvt_pkrtz(a, b));
}
__device__ __forceinline__ unsigned int pk2(float a, float b) {
    return __builtin_bit_cast(unsigned int, __builtin_amdgcn_cvt_pkrtz(a, b));
}

__global__ __launch_bounds__(512, 2)
void awq_gemm_kernel(const float* __restrict__ X,
                     const int*   __restrict__ QW,
                     const int*   __restrict__ QZ,
                     const float* __restrict__ S,
                     const float* __restrict__ BIAS,
                     float*       __restrict__ O)
{
    // A [256 rows][128B] at 0 (single buf); B buf b: [128 cols][128B] at 32768+b*16384
    // A: k-octet o of row r at 16B slot o^(r&7)
    // B: k-octet o of col n at 16B slot o^(n&7)^((n>>3)&7)
    __shared__ alignas(16) unsigned char smem[ABYTES + 2 * BBYTES];  // 65536

    const int t    = threadIdx.x;
    const int lane = t & 63;
    const int w    = t >> 6;      // 0..7
    const int wm   = w >> 1;      // 0..3 (row block of 64)
    const int wn   = w & 1;       // 0..1 (col block of 64)
    const int l15 = lane & 15, l45 = lane >> 4, l7 = lane & 7, l3 = (lane >> 3) & 1;

    // XCD mapping: XCD x (= bid&7) owns mtile x; sweeps all 86 ntiles. 688 = 8*86.
    const int bid   = blockIdx.x;
    const int mtile = bid & 7;
    const int ntile = bid >> 3;
    const int m0 = mtile * BM;
    const int n0 = ntile * BN;
    const int P0 = n0 >> 3;

    // ---- A staging: thread covers rows (t>>3)+64i, k-octet t&7 ----
    const int arow = t >> 3;              // 0..63
    const int aoct = t & 7;
    const int aphys = aoct ^ (arow & 7);  // 64i preserves row&7
    const float* Xb = X + (size_t)(m0 + arow) * IN_F + aoct * 8;

    float4 areg[4][2];
    auto load_A = [&](int kt) {
#pragma unroll
        for (int i = 0; i < 4; ++i) {
            const float* p = Xb + (size_t)i * 64 * IN_F + kt * BK;
            areg[i][0] = *(const float4*)(p);
            areg[i][1] = *(const float4*)(p + 4);
        }
    };
    auto write_A = [&]() {
        unsigned char* ab = smem;
#pragma unroll
        for (int i = 0; i < 4; ++i) {
            uint4 v;
            v.x = pk2(areg[i][0].x, areg[i][0].y);
            v.y = pk2(areg[i][0].z, areg[i][0].w);
            v.z = pk2(areg[i][1].x, areg[i][1].y);
            v.w = pk2(areg[i][1].z, areg[i][1].w);
            *(uint4*)(ab + (i * 64 + arow) * 128 + aphys * 16) = v;
        }
    };

    // ---- B staging: thread covers packed col pcol = t&15, k-pair 2kd, 2kd+1 (kd = t>>4) ----
    const int pcol = t & 15;
    const int kd   = t >> 4;         // 0..31
    const int pc7  = pcol & 7;
    const int ob   = kd >> 2;        // k-octet
    const int sub  = (kd & 3) * 4;   // byte offset within 16B slot
    const int* qwb = QW + (size_t)(2 * kd) * PCOLS + P0 + pcol;
    const unsigned int* qzc = (const unsigned int*)QZ + P0 + pcol;
    const float* scol = S + n0 + pcol * 8;

    constexpr int SH[8]  = {0, 16, 4, 20, 8, 24, 12, 28}; // shift of logical nibble j
    constexpr int JLO[4] = {0, 4, 1, 5};                  // low-nibble j of byte b

    h2 spk[8], zpk[8];
    unsigned int zraw_n; float4 sv0, sv1;
    unsigned int raw0, raw1;

    auto load_group = [&](int g) {
        zraw_n = qzc[(size_t)g * PCOLS];
        sv0 = *(const float4*)(scol + (size_t)g * OUT_F);
        sv1 = *(const float4*)(scol + (size_t)g * OUT_F + 4);
    };
    auto compute_group = [&]() {
        const float sf[8] = {sv0.x, sv0.y, sv0.z, sv0.w, sv1.x, sv1.y, sv1.z, sv1.w};
#pragma unroll
        for (int j = 0; j < 8; ++j) {
            float zb = 1024.0f + (float)((zraw_n >> SH[j]) & 15u);  // exact in f16
            spk[j] = pkh2(sf[j], sf[j]);
            zpk[j] = pkh2(zb, zb);
        }
    };
    auto load_raws = [&](int kt) {
        const size_t off = (size_t)kt * BK * PCOLS;
        raw0 = (unsigned int)qwb[off];
        raw1 = (unsigned int)qwb[off + PCOLS];
    };
    auto stage_B = [&](int buf) {
        unsigned char* bb = smem + ABYTES + buf * BBYTES;
#pragma unroll
        for (int b = 0; b < 4; ++b) {
            const int jl = JLO[b], jh = jl + 2;
            // byte b of raw0 -> dst byte0, byte b of raw1 -> dst byte2 (others masked)
            unsigned int d  = __builtin_amdgcn_perm(raw1, raw0,
                                 (unsigned int)(((4 + b) << 16) | b));
            unsigned int lo = (d & 0x000F000Fu) | 0x64006400u;         // (1024+q) pair, j=jl
            unsigned int hi = ((d >> 4) & 0x000F000Fu) | 0x64006400u;  // j=jh
            // exact sub (both exact ints in f16), then single f16 rounding on mul
            h2 wl = (__builtin_bit_cast(h2, lo) - zpk[jl]) * spk[jl];
            h2 wh = (__builtin_bit_cast(h2, hi) - zpk[jh]) * spk[jh];
            const int nl = pcol * 8 + jl, nh = pcol * 8 + jh;
            *(unsigned int*)(bb + nl * 128 + ((ob ^ jl ^ pc7) * 16) + sub) =
                __builtin_bit_cast(unsigned int, wl);
            *(unsigned int*)(bb + nh * 128 + ((ob ^ jh ^ pc7) * 16) + sub) =
                __builtin_bit_cast(unsigned int, wh);
        }
    };

    f32x4 acc[4][4];
#pragma unroll
    for (int mi = 0; mi < 4; ++mi)
#pragma unroll
        for (int ni = 0; ni < 4; ++ni)
            acc[mi][ni] = f32x4{0.f, 0.f, 0.f, 0.f};

    auto compute_tile = [&](int buf) {
        const unsigned char* ab = smem;
        const unsigned char* bb = smem + ABYTES + buf * BBYTES;
#pragma unroll
        for (int ks = 0; ks < 2; ++ks) {
            h8 a[4], bf[4];
#pragma unroll
            for (int mi = 0; mi < 4; ++mi) {
                int off = (wm * 64 + mi * 16 + l15) * 128
                        + (((ks * 4 + l45) ^ l7) * 16);          // row&7 == l7
                a[mi] = *(const h8*)(ab + off);
            }
#pragma unroll
            for (int ni = 0; ni < 4; ++ni) {
                int off = (wn * 64 + ni * 16 + l15) * 128
                        + ((((ks * 4 + l45) ^ l7 ^ l3) ^ (2 * ni)) * 16); // n&7==l7
                bf[ni] = *(const h8*)(bb + off);
            }
#pragma unroll
            for (int mi = 0; mi < 4; ++mi)
#pragma unroll
                for (int ni = 0; ni < 4; ++ni)
                    acc[mi][ni] = __builtin_amdgcn_mfma_f32_16x16x32_f16(
                        a[mi], bf[ni], acc[mi][ni], 0, 0, 0);
        }
    };

    // ---- prologue: stage tile 0 (A buf + B buf0) ----
    load_A(0);
    load_raws(0);
    load_group(0);
    compute_group();
    write_A();
    stage_B(0);
    __syncthreads();

    // ---- main loop ----
    // [issue global loads k+1] [compute k (A-buf, B-buf[cur])]
    // [dequant+write B k+1 -> B-buf[cur^1]]   (before barrier: disjoint)
    // [sync: A reads done] [write_A k+1 -> A-buf] [sync]
#pragma unroll 2
    for (int kt = 0; kt < NKT; ++kt) {
        const int cur = kt & 1;
        if (kt + 1 < NKT) {
            load_A(kt + 1);                    // issue-early (T14)
            load_raws(kt + 1);
            if (((kt + 1) & 1) == 0) load_group((kt + 1) >> 1);
        }
        compute_tile(cur);
        if (kt + 1 < NKT) {
            if (((kt + 1) & 1) == 0) compute_group();
            stage_B(cur ^ 1);                  // other B buffer: no barrier needed
        }
        __syncthreads();                       // A-buf reads complete
        if (kt + 1 < NKT) {
            write_A();                         // overwrite single A buffer
        }
        __syncthreads();                       // A writes visible
    }

    // ---- epilogue: bias + f32 store (C/D: col=lane&15, row=(lane>>4)*4+reg) ----
    const int orow0 = m0 + wm * 64 + l45 * 4;
    const int ocol0 = n0 + wn * 64 + l15;
    float bv[4];
#pragma unroll
    for (int ni = 0; ni < 4; ++ni)
        bv[ni] = BIAS[ocol0 + ni * 16];
#pragma unroll
    for (int mi = 0; mi < 4; ++mi)
#pragma unroll
        for (int ni = 0; ni < 4; ++ni)
#pragma unroll
            for (int r = 0; r < 4; ++r) {
                int row = orow0 + mi * 16 + r;
                int col = ocol0 + ni * 16;
                O[(size_t)row * OUT_F + col] = acc[mi][ni][r] + bv[ni];
            }
}

extern "C" void kernel_launch(void* const* d_in, const int* in_sizes, int n_in,
                              void* d_out, int out_size, void* d_ws, size_t ws_size,
                              hipStream_t stream) {
    const float* X  = (const float*)d_in[0];
    const int*   QW = (const int*)d_in[1];
    const int*   QZ = (const int*)d_in[2];
    const float* S  = (const float*)d_in[3];
    const float* Bi = (const float*)d_in[4];
    float*       O  = (float*)d_out;

    dim3 grid(8 * NTILES);   // 688
    dim3 block(512);
    awq_gemm_kernel<<<grid, block, 0, stream>>>(X, QW, QZ, S, Bi, O);
}